// Round 1
// baseline (304.809 us; speedup 1.0000x reference)
//
#include <hip/hip_runtime.h>
#include <hip/hip_bf16.h>
#include <math.h>

// Problem constants (reference: B,T,D=64, E=HA=HB=128, OUT=1, short=2)
#define B_ 64
#define T_ 64
#define D_ 64
#define PMIN 3        // short+1
#define NPOUT 60      // T-2-short
#define NCHUNK 8      // batch chunks of 8 per prefix

#define LOG2E     1.4426950408889634f
#define TWOLOG2E  2.8853900817779268f

typedef __hip_bfloat16 bf16;
typedef __attribute__((ext_vector_type(4))) short s16x4;
typedef __attribute__((ext_vector_type(8))) short s16x8;
typedef __attribute__((ext_vector_type(4))) float f32x4;

// ---- workspace layout (fp32 element offsets; packs 16B-aligned) ----
#define OFF_EMB   0                      // [t][b][128] fp32 (written by prep_gi)
#define OFF_WIC2  524288                 // wic2 [g768][e128] fp32 (raw Wi_a||Wi_b)
#define OFF_XT    622592                 // xt [t][d][b] fp32
#define OFF_GIPK  884736                 // bf16 [t][chunk8][w][lane32][24] (prescaled)
#define OFF_WPK   2457600                // bf16 [w][nt6][kt][lane][8] (pi-k, prescaled)
#define OFF_BPPK  2506752                // bf16 [w8][kt][lane][8]     (pi-k, x log2e)
#define OFF_WMPK  2514944                // bf16 [nt4][kt][lane][8]    (true e)
#define OFF_WALPK 2519040                // bf16 [kt][lane][8]         (pi-k, x 0.5log2e)
#define OFF_FLAG  2520064

__device__ __forceinline__ float bf2f(unsigned short u) {
    union { float f; unsigned u32; } x; x.u32 = ((unsigned)u) << 16; return x.f;
}
__device__ __forceinline__ unsigned short f2bf(float f) {
    union { float f; unsigned u; } x; x.f = f;
    unsigned r = x.u + 0x7FFFu + ((x.u >> 16) & 1u);
    return (unsigned short)(r >> 16);
}
__device__ __forceinline__ float LDF(const void* p, int i, int flag) {
    return flag ? ((const float*)p)[i] : bf2f(((const unsigned short*)p)[i]);
}
// cheap activations on prescaled args (see prep: args arrive in log2 domain)
__device__ __forceinline__ float sig2(float xneg) {        // sigmoid, arg = -log2e*x
    return __builtin_amdgcn_rcpf(1.f + __builtin_exp2f(xneg));
}
__device__ __forceinline__ float tanh2(float x2) {         // tanh, arg = 2log2e*x
    return 1.f - 2.f * __builtin_amdgcn_rcpf(1.f + __builtin_exp2f(x2));
}
// k-dimension permutation: stored slot s -> true index (pairs (l,t) adjacent)
__device__ __forceinline__ int kpi(int s) {
    return (s & ~31) | ((s & 1) << 4) | ((s & 31) >> 1);
}

// ---------------- dtype detection ----------------
__global__ void detect_dtype(const unsigned short* xr, int* flag)
{
    int tid = threadIdx.x;
    int bad = 0;
    for (int i = tid; i < 4096; i += 256) {
        int ex = (xr[i] >> 7) & 0xFF;
        if (ex >= 140) bad++;
    }
    __shared__ int s[256];
    s[tid] = bad;
    __syncthreads();
    for (int st = 128; st > 0; st >>= 1) {
        if (tid < st) s[tid] += s[tid + st];
        __syncthreads();
    }
    if (tid == 0) *flag = (s[0] > 4) ? 1 : 0;
}

// ---------------- prep_all: copies/packs only (no emb) ----------------
// sections: wic2 [0,98304) | xt [98304,360448) | wpk [360448,458752)
//           bppk [458752,475136) | wmpk [475136,483328) | walpk [483328,485376)
// 1896 blocks x 256
__global__ void prep_all(const void* p_x, const void* p_wemb,
                         const void* p_wia, const void* p_wib,
                         const void* p_wha, const void* p_whb,
                         const void* p_wa, const void* p_wb, const void* p_wo,
                         float* ws, const int* flagp)
{
    const int flag = *flagp;
    int id = blockIdx.x * 256 + threadIdx.x;
    if (id < 98304) {                                 // wic2 [g][e] straight convert
        float v = (id < 49152) ? LDF(p_wia, id, flag)
                               : LDF(p_wib, id - 49152, flag);
        ws[OFF_WIC2 + id] = v;
    } else if (id < 360448) {                         // xt [t][d][b]
        int id5 = id - 98304;
        int b = id5 & 63, d = (id5 >> 6) & 63, t = id5 >> 12;
        ws[OFF_XT + id5] = LDF(p_x, (b * 64 + t) * 64 + d, flag);
    } else if (id < 458752) {                         // gh weights (pi-k, prescaled)
        unsigned short* wpk = (unsigned short*)(ws + OFF_WPK);
        int id3 = id - 360448;
        int w = id3 / 12288, r1 = id3 % 12288;
        int nt = r1 / 2048, r2 = r1 % 2048;
        int kt = r2 / 512, r3 = r2 % 512;
        int lane = r3 >> 3, j = r3 & 7;
        int cell = w >> 2, wv = w & 3;
        int gate = nt >> 1, tt = nt & 1;
        int g = gate * 128 + wv * 32 + tt * 16 + (lane & 15);
        int k = kpi(kt * 32 + (lane >> 4) * 8 + j);
        float sc = (gate < 2) ? -LOG2E : TWOLOG2E;
        wpk[id3] = f2bf(sc * LDF(cell ? p_whb : p_wha, g * 128 + k, flag));
    } else if (id < 475136) {                         // Wb (pi-k, x log2e)
        unsigned short* bpk = (unsigned short*)(ws + OFF_BPPK);
        int id4 = id - 458752;
        int w = id4 / 2048, r = id4 % 2048;
        int kt = r / 512, lane = (r % 512) >> 3, j = r & 7;
        int e = w * 16 + (lane & 15);
        int k = kpi(kt * 32 + (lane >> 4) * 8 + j);
        bpk[id4] = f2bf(LOG2E * LDF(p_wb, e * 128 + k, flag));
    } else if (id < 483328) {                         // Wm (true e, unscaled)
        unsigned short* wmk = (unsigned short*)(ws + OFF_WMPK);
        int id6 = id - 475136;
        int nt = id6 / 2048, r = id6 % 2048;
        int kt = r / 512, lane = (r % 512) >> 3, j = r & 7;
        int d = nt * 16 + (lane & 15);
        int e = kt * 32 + (lane >> 4) * 8 + j;
        wmk[id6] = f2bf(LDF(p_wo, e, flag) * LDF(p_wemb, e * 64 + d, flag));
    } else {                                          // Wa alpha tile (pi-k, x 0.5log2e)
        unsigned short* alk = (unsigned short*)(ws + OFF_WALPK);
        int id7 = id - 483328;
        int kt = id7 / 512, lane = (id7 % 512) >> 3, j = id7 & 7;
        int k = kpi(kt * 32 + (lane >> 4) * 8 + j);
        alk[id7] = ((lane & 15) == 0) ? f2bf(0.5f * LOG2E * LDF(p_wa, k, flag))
                                      : (unsigned short)0;
    }
}

// ---------------- prep_gi: computes emb in-kernel, then gi (prescaled) ----------------
// 512 blocks = (t, chunk8) x 256 threads.
__global__ void prep_gi(float* ws, const void* p_x, const void* p_wemb,
                        const void* p_bemb, const void* p_bia, const void* p_bha,
                        const void* p_bib, const void* p_bhb, const int* flagp)
{
    const int flag = *flagp;
    unsigned short* gipk = (unsigned short*)(ws + OFF_GIPK);
    int t = blockIdx.x >> 3;
    int chunk = blockIdx.x & 7;
    int b0 = chunk * 8;
    int tid = threadIdx.x;
    __shared__ __align__(16) float sX[8][64];
    __shared__ __align__(16) float sWe[128][64];
    __shared__ __align__(16) float semT2[8][132];
    __shared__ __align__(16) unsigned short stg[6144];

    for (int i = tid; i < 512; i += 256) {
        int r = i >> 6, d = i & 63;
        sX[r][d] = LDF(p_x, ((b0 + r) * 64 + t) * 64 + d, flag);
    }
    for (int i = tid; i < 8192; i += 256)
        sWe[i >> 6][i & 63] = LDF(p_wemb, i, flag);
    __syncthreads();

    // emb for this block's 8 rows; write LDS (for gi) + ws (for chain Phase C)
    #pragma unroll
    for (int q = 0; q < 4; q++) {
        int o = tid + q * 256;
        int e = o & 127, r = o >> 7;
        float acc = LDF(p_bemb, e, flag);
        #pragma unroll
        for (int d = 0; d < 64; d += 4) {
            f32x4 xv = *(const f32x4*)&sX[r][d];
            f32x4 wv = *(const f32x4*)&sWe[e][d];
            acc += xv[0]*wv[0] + xv[1]*wv[1] + xv[2]*wv[2] + xv[3]*wv[3];
        }
        semT2[r][e] = acc;
        ws[OFF_EMB + (size_t)((t * 64 + b0 + r) * 128) + e] = acc;
    }
    __syncthreads();

    // gi = emb @ Wi^T  (wic2 [g][e] read as dwordx4)
    float acc3[3][8];
    #pragma unroll
    for (int g3 = 0; g3 < 3; g3++)
        #pragma unroll
        for (int r = 0; r < 8; r++) acc3[g3][r] = 0.f;
    const float* w2 = ws + OFF_WIC2;
    #pragma unroll 2
    for (int e0 = 0; e0 < 128; e0 += 4) {
        f32x4 wv0 = *(const f32x4*)(w2 + (size_t)(tid      ) * 128 + e0);
        f32x4 wv1 = *(const f32x4*)(w2 + (size_t)(tid + 256) * 128 + e0);
        f32x4 wv2 = *(const f32x4*)(w2 + (size_t)(tid + 512) * 128 + e0);
        f32x4 h[8];
        #pragma unroll
        for (int r = 0; r < 8; r++) h[r] = *(const f32x4*)&semT2[r][e0];
        #pragma unroll
        for (int r = 0; r < 8; r++)
            #pragma unroll
            for (int c = 0; c < 4; c++) {
                acc3[0][r] += wv0[c] * h[r][c];
                acc3[1][r] += wv1[c] * h[r][c];
                acc3[2][r] += wv2[c] * h[r][c];
            }
    }
    // epilogue: fold bi (+bh for r,z), prescale, scatter to stg
    #pragma unroll
    for (int g3 = 0; g3 < 3; g3++) {
        int g = tid + g3 * 256;
        int cellg = g / 384, gr = g % 384;
        int gate = gr / 128, kh = gr % 128;
        int wvp = kh / 32, tt2 = (kh % 32) / 16, l15p = kh % 16;
        int wq = cellg * 4 + wvp;
        float bias = LDF(cellg ? p_bib : p_bia, gr, flag);
        if (gate < 2) bias += LDF(cellg ? p_bhb : p_bha, gr, flag);
        float sc = (gate < 2) ? -LOG2E : TWOLOG2E;
        #pragma unroll
        for (int r = 0; r < 8; r++) {
            float v = sc * (acc3[g3][r] + bias);
            int lane2 = (r >> 2) * 16 + l15p;
            int slot = gate * 8 + tt2 * 4 + (r & 3);
            stg[(wq * 32 + lane2) * 24 + slot] = f2bf(v);
        }
    }
    __syncthreads();
    const uint4* s4 = (const uint4*)stg;                  // 768 uint4
    uint4* d4 = (uint4*)(gipk + (size_t)(t * 8 + chunk) * 6144);
    for (int i = tid; i < 768; i += 256) d4[i] = s4[i];
}

// ---------------- fused chain kernel ----------------
// 480 WGs (prefix p long-first, chunk of 8), 512 threads, 2 WGs/CU.
// Diet vs R10: prescaled exp2 activations, quad-split GRU (quads 2-3 take
// tt=1 gates via shfl_xor 32), stride-136 16B-aligned LDS, b128 A-frags.

__launch_bounds__(512, 2)
__global__ void chain_kernel(const float* ws, void* outv, const int* flagp,
                             const void* p_bha, const void* p_bhb,
                             const void* p_bb, const void* p_ba,
                             const void* p_bo, const void* p_wo)
{
    const int p = PMIN + (NPOUT - 1) - (int)blockIdx.x / NCHUNK;
    const int chunk = (int)blockIdx.x % NCHUNK;
    const int tid = threadIdx.x;
    const int lane = tid & 63;
    const int w = tid >> 6;
    const int cell = w >> 2;
    const int wv = w & 3;
    const int l15 = lane & 15;
    const int quad = lane >> 4;
    const int tt = quad >> 1;       // 0: quads 0-1, 1: quads 2-3 (GRU split)
    const int rquad = quad & 1;     // row-quad for GRU h rows

    __shared__ __align__(16) short hbf[2][2][16][136];   // [buf][cell][row][m] pi-k
    __shared__ __align__(16) short betbf[2][16][136];    // true-e order
    __shared__ __align__(16) short sWm[4][4][64][8];
    __shared__ float spaLds[2][8];

    const unsigned short* gipk = (const unsigned short*)(ws + OFF_GIPK);
    const unsigned short* wpk  = (const unsigned short*)(ws + OFF_WPK);
    const unsigned short* bpk  = (const unsigned short*)(ws + OFF_BPPK);
    const unsigned short* alk  = (const unsigned short*)(ws + OFF_WALPK);
    const int flag = *flagp;

    {   // stage Wm; zero ALL h and beta buffers (rows 8-15 stay zero forever)
        const int* s2 = (const int*)(ws + OFF_WMPK);
        int* d2 = (int*)&sWm[0][0][0][0];
        for (int i = tid; i < 4096; i += 512) d2[i] = s2[i];
        int* hz = (int*)&hbf[0][0][0][0];
        for (int i = tid; i < 4352; i += 512) hz[i] = 0;
        int* bz = (int*)&betbf[0][0][0];
        for (int i = tid; i < 2176; i += 512) bz[i] = 0;
    }

    // persistent B-fragment registers
    s16x8 wB[6][4];
    #pragma unroll
    for (int nt = 0; nt < 6; nt++)
        #pragma unroll
        for (int kt = 0; kt < 4; kt++)
            wB[nt][kt] = *(const s16x8*)(wpk + (((w * 6 + nt) * 4 + kt) * 64 + lane) * 8);
    s16x8 bBp[4], wAl[4];
    #pragma unroll
    for (int kt = 0; kt < 4; kt++) {
        bBp[kt] = *(const s16x8*)(bpk + ((w * 4 + kt) * 64 + lane) * 8);
        wAl[kt] = *(const s16x8*)(alk + (kt * 64 + lane) * 8);
    }

    // per-lane constants (prescaled)
    const float bhnS = TWOLOG2E *
        LDF(cell ? p_bhb : p_bha, 256 + wv * 32 + tt * 16 + l15, flag);
    const float bbE2 = TWOLOG2E * LDF(p_bb, w * 16 + l15, flag);
    const float bafS = LOG2E * LDF(p_ba, 0, flag);
    const float bof  = LDF(p_bo, 0, flag);

    float h_old[4];                 // this lane's tt-half of h rows
    #pragma unroll
    for (int i = 0; i < 4; i++) h_old[i] = 0.f;
    // union accumulator: w<4 -> [0..3]=gAcc, [4..7]=sl4; w>=4 -> [0..7]=cAcc, [8]=slB
    float accR[9];
    #pragma unroll
    for (int i = 0; i < 9; i++) accR[i] = 0.f;

    __syncthreads();

    for (int it = 0; it <= p + 1; it++) {
        const int j = p - it;
        const int jp = j + 1;
        const bool doGru = (j >= 0);
        const bool doAcc = (it > 0);
        const int cur = it & 1;
        const int nxt = cur ^ 1;
        const int dbuf = it & 1;

        // gi for current j (per-lane tt slice, b64 loads)
        s16x4 giv[3];
        if (doGru) {
            const unsigned short* gp0 =
                gipk + ((((size_t)j * 8 + chunk) * 8 + w) * 32 + (lane & 31)) * 24;
            giv[0] = *(const s16x4*)(gp0 + tt * 4);
            giv[1] = *(const s16x4*)(gp0 + 8 + tt * 4);
            giv[2] = *(const s16x4*)(gp0 + 16 + tt * 4);
        }
        // prefetch x / emb for this iteration's Phase C
        f32x4 xv, em0, em1;
        if (doAcc) {
            if (w < 4) {
                xv = *(const f32x4*)(ws + OFF_XT + ((size_t)jp * 64 + w * 16 + l15) * 64
                                     + chunk * 8 + rquad * 4);
            } else {
                const int row8 = (quad * 4 + (w - 4)) & 7;
                const float* ep = ws + OFF_EMB
                                  + ((size_t)jp * 64 + chunk * 8 + row8) * 128 + l15 * 8;
                em0 = *(const f32x4*)ep;
                em1 = *(const f32x4*)(ep + 4);
            }
        }

        // ---- Phase A: MFMA gates + betapre (+ alpha on w==7) ----
        f32x4 Cg[6], Cbp, Cal;
        #pragma unroll
        for (int nt = 0; nt < 6; nt++) Cg[nt] = (f32x4){0.f,0.f,0.f,0.f};
        Cbp = (f32x4){0.f,0.f,0.f,0.f};
        Cal = (f32x4){0.f,0.f,0.f,0.f};

        #pragma unroll
        for (int kt = 0; kt < 4; kt++) {
            s16x8 aB = *(const s16x8*)&hbf[cur][1][l15][kt * 32 + quad * 8];
            s16x8 aA;
            if (cell == 0 || w == 7) aA = *(const s16x8*)&hbf[cur][0][l15][kt * 32 + quad * 8];
            else aA = aB;
            s16x8 aOwn = cell ? aB : aA;
            #pragma unroll
            for (int nt = 0; nt < 6; nt++)
                Cg[nt] = __builtin_amdgcn_mfma_f32_16x16x32_bf16(aOwn, wB[nt][kt], Cg[nt], 0, 0, 0);
            Cbp = __builtin_amdgcn_mfma_f32_16x16x32_bf16(aB, bBp[kt], Cbp, 0, 0, 0);
            if (w == 7)
                Cal = __builtin_amdgcn_mfma_f32_16x16x32_bf16(aA, wAl[kt], Cal, 0, 0, 0);
        }

        // ---- Phase B ----
        if (w == 7 && l15 == 0 && quad < 2) {   // spa in log2 domain
            #pragma unroll
            for (int reg = 0; reg < 4; reg++)
                spaLds[dbuf][quad * 4 + reg] = fminf(Cal[reg] + bafS, 86.f);
        }
        if (doGru) {   // quad-split GRU: all 64 lanes, each does its tt half
            #pragma unroll
            for (int reg = 0; reg < 4; reg++) {
                float s1 = __shfl_xor(Cg[1][reg], 32);
                float s3 = __shfl_xor(Cg[3][reg], 32);
                float s5 = __shfl_xor(Cg[5][reg], 32);
                float ghr = tt ? s1 : Cg[0][reg];
                float ghz = tt ? s3 : Cg[2][reg];
                float ghn = (tt ? s5 : Cg[4][reg]) + bhnS;
                float gir = bf2f((unsigned short)giv[0][reg]);
                float giz = bf2f((unsigned short)giv[1][reg]);
                float gin = bf2f((unsigned short)giv[2][reg]);
                float rr = sig2(gir + ghr);
                float zz = sig2(giz + ghz);
                float nn = tanh2(gin + rr * ghn);
                float hv2 = (1.f - zz) * nn + zz * h_old[reg];
                h_old[reg] = hv2;
                hbf[nxt][cell][rquad * 4 + reg][wv * 32 + l15 * 2 + tt] = (short)f2bf(hv2);
            }
        }
        if (quad < 2) {   // beta = tanh (prescaled arg)
            #pragma unroll
            for (int reg = 0; reg < 4; reg++) {
                float bv = tanh2(Cbp[reg] + bbE2);
                betbf[dbuf][quad * 4 + reg][w * 16 + l15] = (short)f2bf(bv);
            }
        }

        __syncthreads();   // the ONE barrier

        // ---- Phase C: attention accumulation (scan step it-1) ----
        if (doAcc) {
            if (w < 4) {
                f32x4 ec = (f32x4){0.f,0.f,0.f,0.f};
                #pragma unroll
                for (int kt = 0; kt < 4; kt++) {
                    s16x8 a = *(const s16x8*)&betbf[dbuf][l15][kt * 32 + quad * 8];
                    s16x8 bw = *(const s16x8*)&sWm[w][kt][lane][0];
                    ec = __builtin_amdgcn_mfma_f32_16x16x32_bf16(a, bw, ec, 0, 0, 0);
                }
                #pragma unroll
                for (int reg = 0; reg < 4; reg++) {
                    float we = __builtin_exp2f(spaLds[dbuf][(quad * 4 + reg) & 7]);
                    accR[4 + reg] += we;
                    accR[reg] += we * ec[reg] * xv[reg];
                }
            } else {
                const int row8 = (quad * 4 + (w - 4)) & 7;
                float we = __builtin_exp2f(spaLds[dbuf][row8]);
                accR[8] += we;
                const short* bp2 = &betbf[dbuf][row8][l15 * 8];
                s16x4 blo = *(const s16x4*)bp2;
                s16x4 bhi = *(const s16x4*)(bp2 + 4);
                #pragma unroll
                for (int v = 0; v < 4; v++)
                    accR[v] += we * bf2f((unsigned short)blo[v]) * em0[v];
                #pragma unroll
                for (int v = 0; v < 4; v++)
                    accR[4 + v] += we * bf2f((unsigned short)bhi[v]) * em1[v];
            }
        }
    }

    // ---- epilogue ----
    if (w >= 4) {       // pred = (c . Wo)/sl + bo
        const int row = quad * 4 + (w - 4);
        float wo8[8];
        if (flag) {
            const float* wp = (const float*)p_wo + l15 * 8;
            #pragma unroll
            for (int v = 0; v < 8; v++) wo8[v] = wp[v];
        } else {
            const unsigned short* wp = (const unsigned short*)p_wo + l15 * 8;
            #pragma unroll
            for (int v = 0; v < 8; v++) wo8[v] = bf2f(wp[v]);
        }
        float part = 0.f;
        #pragma unroll
        for (int v = 0; v < 8; v++) part += accR[v] * wo8[v];
        part += __shfl_xor(part, 1);
        part += __shfl_xor(part, 2);
        part += __shfl_xor(part, 4);
        part += __shfl_xor(part, 8);
        if (l15 == 0 && row < 8) {
            int bglob = chunk * 8 + row;
            float pr = part / accR[8] + bof;
            size_t oi = (size_t)bglob * NPOUT + (p - PMIN);
            if (flag) ((float*)outv)[oi] = pr;
            else      ((bf16*)outv)[oi] = __float2bfloat16(pr);
        }
    } else if (quad < 2) {   // weight = g/sl/(p+1), rows 0..7
        const float invt = 1.f / (float)(p + 1);
        #pragma unroll
        for (int reg = 0; reg < 4; reg++) {
            int row = quad * 4 + reg;
            int bglob = chunk * 8 + row;
            float gv = accR[reg] / accR[4 + reg] * invt;
            size_t oi = (size_t)B_ * NPOUT
                      + ((size_t)bglob * NPOUT + (p - PMIN)) * 64 + w * 16 + l15;
            if (flag) ((float*)outv)[oi] = gv;
            else      ((bf16*)outv)[oi] = __float2bfloat16(gv);
        }
    }
}

// ---------------- launch ----------------
extern "C" void kernel_launch(void* const* d_in, const int* in_sizes, int n_in,
                              void* d_out, int out_size, void* d_ws, size_t ws_size,
                              hipStream_t stream)
{
    float* ws = (float*)d_ws;
    int* flagp = (int*)(ws + OFF_FLAG);

    hipLaunchKernelGGL(detect_dtype, dim3(1), dim3(256), 0, stream,
                       (const unsigned short*)d_in[0], flagp);
    hipLaunchKernelGGL(prep_all, dim3(1896), dim3(256), 0, stream,
                       d_in[0], d_in[1], d_in[3], d_in[7], d_in[4], d_in[8],
                       d_in[11], d_in[13], d_in[15], ws, flagp);
    hipLaunchKernelGGL(prep_gi, dim3(512), dim3(256), 0, stream,
                       ws, d_in[0], d_in[1], d_in[2], d_in[5], d_in[6],
                       d_in[9], d_in[10], flagp);
    hipLaunchKernelGGL(chain_kernel, dim3(NPOUT * NCHUNK), dim3(512), 0, stream,
                       ws, d_out, flagp,
                       d_in[6], d_in[10], d_in[14], d_in[12], d_in[16], d_in[15]);
}